// Round 16
// baseline (83.256 us; speedup 1.0000x reference)
//
#include <hip/hip_runtime.h>
#include <hip/hip_fp16.h>
#include <math.h>

typedef _Float16 half8_t  __attribute__((ext_vector_type(8)));
typedef _Float16 h2_t     __attribute__((ext_vector_type(2)));
typedef float    f32x16_t __attribute__((ext_vector_type(16)));

#define NCELL 324            // 18x18 zero-border grid
#define CST   24             // f16 per cell row (48 B, 16B-aligned)
#define G1H   (NCELL * CST)  // 7776 f16 = 15552 B

static __device__ __forceinline__ float sigmoid_f(float z) {
    return __builtin_amdgcn_rcpf(1.0f + __expf(-z));
}
static __device__ __forceinline__ h2_t bc_h2(int v) { return __builtin_bit_cast(h2_t, v); }
static __device__ __forceinline__ int  bc_i(h2_t v) { return __builtin_bit_cast(int, v); }

static __device__ __forceinline__ h2_t pk_max(h2_t a, h2_t b) {
#if __has_builtin(__builtin_elementwise_max)
    return __builtin_elementwise_max(a, b);
#else
    h2_t r; r[0] = a[0] > b[0] ? a[0] : b[0]; r[1] = a[1] > b[1] ? a[1] : b[1]; return r;
#endif
}
static __device__ __forceinline__ h2_t mkh2(float a, float b) {
    h2_t t; t[0] = (_Float16)a; t[1] = (_Float16)b; return t;
}
// f16x2 dot with f32 accumulate
static __device__ __forceinline__ float dot2f(h2_t w, h2_t h, float c) {
#if __has_builtin(__builtin_amdgcn_fdot2)
    return __builtin_amdgcn_fdot2(w, h, c, false);
#else
    return fmaf((float)w[1], (float)h[1], fmaf((float)w[0], (float)h[0], c));
#endif
}

// Shared bilinear core: 4 corner int4s -> post-leaky f16 B-fragment.
static __device__ __forceinline__ half8_t bilerp8(int4 A, int4 B, int4 C, int4 D,
                                                  float2 cc) {
    float ix = fmaf(cc.x, 8.f, 8.5f);   // +1 cell shift for zero border
    float iy = fmaf(cc.y, 8.f, 8.5f);
    float xf = floorf(ix), yf = floorf(iy);
    float wx1 = ix - xf, wy1 = iy - yf;
    float wx0 = 1.f - wx1, wy0 = 1.f - wy1;
    float w00 = wy0 * wx0, w01 = wy0 * wx1, w10 = wy1 * wx0, w11 = wy1 * wx1;
    const h2_t W00 = { (_Float16)w00, (_Float16)w00 };
    const h2_t W01 = { (_Float16)w01, (_Float16)w01 };
    const h2_t W10 = { (_Float16)w10, (_Float16)w10 };
    const h2_t W11 = { (_Float16)w11, (_Float16)w11 };
    const h2_t K02 = { (_Float16)0.2f, (_Float16)0.2f };
    auto bl = [&](int a, int b, int c, int d) -> int {
        h2_t v = bc_h2(a) * W00;
        v = bc_h2(b) * W01 + v;
        v = bc_h2(c) * W10 + v;
        v = bc_h2(d) * W11 + v;
        return bc_i(pk_max(v, v * K02));   // leaky 0.2
    };
    int4 t;
    t.x = bl(A.x, B.x, C.x, D.x);
    t.y = bl(A.y, B.y, C.y, D.y);
    t.z = bl(A.z, B.z, C.z, D.z);
    t.w = bl(A.w, B.w, C.w, D.w);
    return __builtin_bit_cast(half8_t, t);
}

static __device__ __forceinline__ int cell_of(float2 cc) {
    float ix = fmaf(cc.x, 8.f, 8.5f);
    float iy = fmaf(cc.y, 8.f, 8.5f);
    int cx = (int)floorf(ix), cy = (int)floorf(iy);
    return cy * 18 + cx;
}

// Bilinear sample of one 8-ch half from LDS (pipe: DS).
static __device__ __forceinline__ half8_t sample_half_lds(const _Float16* __restrict__ sG,
                                                          float2 cc, int hi) {
    const _Float16* gp = sG + cell_of(cc) * CST + 8 * hi;   // 16B-aligned
    const int4 A = *reinterpret_cast<const int4*>(gp);
    const int4 B = *reinterpret_cast<const int4*>(gp + CST);
    const int4 C = *reinterpret_cast<const int4*>(gp + 18 * CST);
    const int4 D = *reinterpret_cast<const int4*>(gp + 19 * CST);
    return bilerp8(A, B, C, D, cc);
}

// Bilinear sample of one 8-ch half from GLOBAL (pipe: VMEM; table L1/L2-resident).
static __device__ __forceinline__ half8_t sample_half_g(const __half* __restrict__ G1g,
                                                        float2 cc, int hi) {
    const __half* gp = G1g + cell_of(cc) * CST + 8 * hi;    // 16B-aligned
    const int4 A = *reinterpret_cast<const int4*>(gp);
    const int4 B = *reinterpret_cast<const int4*>(gp + CST);
    const int4 C = *reinterpret_cast<const int4*>(gp + 18 * CST);
    const int4 D = *reinterpret_cast<const int4*>(gp + 19 * CST);
    return bilerp8(A, B, C, D, cc);
}

// G1[cell][o] = sum_c W1[o][c]*grid[c][cell] + b1[o]  (border cells = b1: bilinear
// weights sum to 1, so bilinear(G1') == bilinear(W1·g) + b1). f16, stride 24.
__global__ __launch_bounds__(64) void fuse_grid_k(const float* __restrict__ grid,
                                                  const float* __restrict__ W1,
                                                  const float* __restrict__ b1,
                                                  __half* __restrict__ G1) {
    int cell = blockIdx.x * 64 + threadIdx.x;
    if (cell >= NCELL) return;
    int yy = (cell * 3641) >> 16;          // /18
    int xx = cell - yy * 18;
    bool border = (yy == 0) | (yy == 17) | (xx == 0) | (xx == 17);
    int base = border ? 0 : ((yy - 1) * 16 + (xx - 1));
    float g[8];
    #pragma unroll
    for (int c = 0; c < 8; ++c) g[c] = grid[c * 256 + base];
    float m = border ? 0.f : 1.f;
    __align__(16) __half tmp[24];
    #pragma unroll
    for (int o = 0; o < 16; ++o) {
        float a = 0.f;
        #pragma unroll
        for (int c = 0; c < 8; ++c) a = fmaf(W1[o * 8 + c], g[c], a);
        tmp[o] = __float2half(fmaf(a, m, b1[o]));
    }
    #pragma unroll
    for (int o = 16; o < 24; ++o) tmp[o] = __float2half(0.f);
    int4* dst = reinterpret_cast<int4*>(G1 + cell * CST);
    const int4* src = reinterpret_cast<const int4*>(tmp);
    dst[0] = src[0]; dst[1] = src[1]; dst[2] = src[2];
}

// 256 threads, (256,4) regalloc regime (r10-proven, no spills).
// Gathers split across pipes: fA via LDS (DS pipe), fB via global (VMEM pipe,
// 15.5KB table is L1/L2-resident) -> each pipe carries half the gather load.
__global__ __launch_bounds__(256, 4) void mlp_main(
    const float* __restrict__ xin, const __half* __restrict__ G1,
    const float* __restrict__ W2, const float* __restrict__ b2,
    const float* __restrict__ W3, const float* __restrict__ b3,
    float* __restrict__ out, int npix)
{
    __shared__ __align__(16) _Float16 sG[G1H];   // 15552 B — the ONLY LDS
    const int tid = threadIdx.x;

    {   // stage fused grid (972 int4 chunks)
        const int4* src = reinterpret_cast<const int4*>(G1);
        int4* dst = reinterpret_cast<int4*>(sG);
        #pragma unroll
        for (int k = 0; k < 4; ++k) {
            int i = tid + k * 256;
            if (i < G1H / 8) dst[i] = src[i];
        }
    }

    const int lane = tid & 63;
    const int hi   = lane >> 5;      // K-half selector
    const int r    = lane & 31;      // A-row / B-col
    const int wv   = tid >> 6;

    // ---- A-frag for layer 2 (32x32x16: row = lane&31, k = 8*hi + j) — r10-verified ----
    half8_t A2;
    #pragma unroll
    for (int j = 0; j < 8; ++j) A2[j] = (_Float16)0.f;
    if (r < 16) {
        const float4 u0 = *reinterpret_cast<const float4*>(W2 + r * 16 + hi * 8);
        const float4 u1 = *reinterpret_cast<const float4*>(W2 + r * 16 + hi * 8 + 4);
        A2[0] = (_Float16)u0.x; A2[1] = (_Float16)u0.y; A2[2] = (_Float16)u0.z; A2[3] = (_Float16)u0.w;
        A2[4] = (_Float16)u1.x; A2[5] = (_Float16)u1.y; A2[6] = (_Float16)u1.z; A2[7] = (_Float16)u1.w;
    }

    // ---- b2 as MFMA C-in (C/D row = (reg&3)+8*(reg>>2)+4*hi) — r10-HW-verified ----
    f32x16_t b2v;
    #pragma unroll
    for (int j = 0; j < 16; ++j) b2v[j] = 0.f;
    {
        const float4 q0 = *reinterpret_cast<const float4*>(b2 + 4 * hi);
        const float4 q1 = *reinterpret_cast<const float4*>(b2 + 8 + 4 * hi);
        b2v[0] = q0.x; b2v[1] = q0.y; b2v[2] = q0.z; b2v[3] = q0.w;
        b2v[4] = q1.x; b2v[5] = q1.y; b2v[6] = q1.z; b2v[7] = q1.w;
    }

    // ---- per-lane layer-3 W3 fragment: acc reg j holds row n(j)=(j<4?4hi+j:4+4hi+j) ----
    h2_t W3L[3][4];
    #pragma unroll
    for (int o = 0; o < 3; ++o) {
        const float4 u0 = *reinterpret_cast<const float4*>(W3 + o * 16 + 4 * hi);
        const float4 u1 = *reinterpret_cast<const float4*>(W3 + o * 16 + 8 + 4 * hi);
        W3L[o][0] = mkh2(u0.x, u0.y); W3L[o][1] = mkh2(u0.z, u0.w);
        W3L[o][2] = mkh2(u1.x, u1.y); W3L[o][3] = mkh2(u1.z, u1.w);
    }
    const float b3s0 = b3[0], b3s1 = b3[1], b3s2 = b3[2];

    __syncthreads();

    const h2_t K02 = { (_Float16)0.2f, (_Float16)0.2f };
    const float2* xp = reinterpret_cast<const float2*>(xin);   // int-indexed

    // ---- hoist all coord loads (latency overlap) ----
    const int wbase = blockIdx.x * 1024 + wv * 256;
    float2 cc0v[4], cc1v[4];
    #pragma unroll
    for (int u = 0; u < 4; ++u) {
        int p0 = wbase + u * 64 + r;
        int p1 = p0 + 32;
        cc0v[u] = (p0 < npix) ? xp[p0] : make_float2(0.f, 0.f);
        cc1v[u] = (p1 < npix) ? xp[p1] : make_float2(0.f, 0.f);
    }

    #pragma unroll
    for (int u = 0; u < 4; ++u) {
        const int base = wbase + u * 64;

        // ---- B-fragments: fA from LDS (DS pipe), fB from global (VMEM pipe) ----
        half8_t fA = sample_half_lds(sG, cc0v[u], hi);   // px base+r,    ch 8hi..
        half8_t fB = sample_half_g(G1, cc1v[u], hi);     // px base+32+r, ch 8hi..

        f32x16_t acc0 = __builtin_amdgcn_mfma_f32_32x32x16_f16(A2, fA, b2v, 0, 0, 0);
        f32x16_t acc1 = __builtin_amdgcn_mfma_f32_32x32x16_f16(A2, fB, b2v, 0, 0, 0);

        // ---- h2 = leaky(acc) in packed f16 (b2 already in via C-in) ----
        h2_t hA[4], hB[4];
        #pragma unroll
        for (int p = 0; p < 4; ++p) {
            h2_t vA = mkh2(acc0[2 * p], acc0[2 * p + 1]);   // v_cvt_pkrtz
            h2_t vB = mkh2(acc1[2 * p], acc1[2 * p + 1]);
            hA[p] = pk_max(vA, vA * K02);
            hB[p] = pk_max(vB, vB * K02);
        }

        // ---- layer 3 half-partials via v_dot2_f32_f16 (8 rows per lane) ----
        float pA0 = dot2f(W3L[0][3], hA[3], dot2f(W3L[0][2], hA[2],
                    dot2f(W3L[0][1], hA[1], dot2f(W3L[0][0], hA[0], 0.f))));
        float pA1 = dot2f(W3L[1][3], hA[3], dot2f(W3L[1][2], hA[2],
                    dot2f(W3L[1][1], hA[1], dot2f(W3L[1][0], hA[0], 0.f))));
        float pA2 = dot2f(W3L[2][3], hA[3], dot2f(W3L[2][2], hA[2],
                    dot2f(W3L[2][1], hA[1], dot2f(W3L[2][0], hA[0], 0.f))));
        float pB0 = dot2f(W3L[0][3], hB[3], dot2f(W3L[0][2], hB[2],
                    dot2f(W3L[0][1], hB[1], dot2f(W3L[0][0], hB[0], 0.f))));
        float pB1 = dot2f(W3L[1][3], hB[3], dot2f(W3L[1][2], hB[2],
                    dot2f(W3L[1][1], hB[1], dot2f(W3L[1][0], hB[0], 0.f))));
        float pB2 = dot2f(W3L[2][3], hB[3], dot2f(W3L[2][2], hB[2],
                    dot2f(W3L[2][1], hB[1], dot2f(W3L[2][0], hB[0], 0.f))));

        // ---- combine half-partials across hi with 3 shfl_xor(32) (r13-verified) ----
        float sel0 = hi ? pA0 : pB0;
        float sel1 = hi ? pA1 : pB1;
        float sel2 = hi ? pA2 : pB2;
        float got0 = __shfl_xor(sel0, 32);
        float got1 = __shfl_xor(sel1, 32);
        float got2 = __shfl_xor(sel2, 32);
        float y0 = (hi ? pB0 : pA0) + got0 + b3s0;
        float y1 = (hi ? pB1 : pA1) + got1 + b3s1;
        float y2 = (hi ? pB2 : pA2) + got2 + b3s2;

        // ---- every lane stores its own pixel ----
        const int pv = base + lane;
        if (pv < npix) {
            float* po = out + pv * 3;
            po[0] = sigmoid_f(y0);
            po[1] = sigmoid_f(y1);
            po[2] = sigmoid_f(y2);
        }
    }
}

extern "C" void kernel_launch(void* const* d_in, const int* in_sizes, int n_in,
                              void* d_out, int out_size, void* d_ws, size_t ws_size,
                              hipStream_t stream)
{
    const float* xin  = (const float*)d_in[0];
    const float* grid = (const float*)d_in[1];
    const float* W1   = (const float*)d_in[2];
    const float* b1   = (const float*)d_in[3];
    const float* W2   = (const float*)d_in[4];
    const float* b2   = (const float*)d_in[5];
    const float* W3   = (const float*)d_in[6];
    const float* b3   = (const float*)d_in[7];
    float* out = (float*)d_out;

    int npix = in_sizes[0] / 2;
    __half* g1 = (__half*)d_ws;   // 15552 B

    fuse_grid_k<<<(NCELL + 63) / 64, 64, 0, stream>>>(grid, W1, b1, g1);
    int nb = (npix + 1023) / 1024;   // 256 threads x 4 px, one tile per block (r14-proven)
    mlp_main<<<nb, 256, 0, stream>>>(xin, g1, W2, b2, W3, b3, out, npix);
}

// Round 17
// 58.022 us; speedup vs baseline: 1.4349x; 1.4349x over previous
//
#include <hip/hip_runtime.h>
#include <hip/hip_fp16.h>
#include <math.h>

typedef _Float16 half8_t  __attribute__((ext_vector_type(8)));
typedef _Float16 h2_t     __attribute__((ext_vector_type(2)));
typedef float    f32x16_t __attribute__((ext_vector_type(16)));

#define NCELL 324            // 18x18 zero-border grid
#define CST   24             // f16 per cell row (48 B, 16B-aligned)
#define G1H   (NCELL * CST)  // 7776 f16 = 15552 B

static __device__ __forceinline__ float sigmoid_f(float z) {
    return __builtin_amdgcn_rcpf(1.0f + __expf(-z));
}
static __device__ __forceinline__ h2_t bc_h2(int v) { return __builtin_bit_cast(h2_t, v); }
static __device__ __forceinline__ int  bc_i(h2_t v) { return __builtin_bit_cast(int, v); }

static __device__ __forceinline__ h2_t pk_max(h2_t a, h2_t b) {
#if __has_builtin(__builtin_elementwise_max)
    return __builtin_elementwise_max(a, b);
#else
    h2_t r; r[0] = a[0] > b[0] ? a[0] : b[0]; r[1] = a[1] > b[1] ? a[1] : b[1]; return r;
#endif
}
static __device__ __forceinline__ h2_t mkh2(float a, float b) {
    h2_t t; t[0] = (_Float16)a; t[1] = (_Float16)b; return t;
}
// f16x2 dot with f32 accumulate
static __device__ __forceinline__ float dot2f(h2_t w, h2_t h, float c) {
#if __has_builtin(__builtin_amdgcn_fdot2)
    return __builtin_amdgcn_fdot2(w, h, c, false);
#else
    return fmaf((float)w[1], (float)h[1], fmaf((float)w[0], (float)h[0], c));
#endif
}

static __device__ __forceinline__ int cell_of(float2 cc) {
    float ix = fmaf(cc.x, 8.f, 8.5f);   // +1 cell shift for zero border
    float iy = fmaf(cc.y, 8.f, 8.5f);
    int cx = (int)floorf(ix), cy = (int)floorf(iy);
    return cy * 18 + cx;
}

// Blend 4 corner int4s -> post-leaky f16 B-fragment (weights recomputed from cc).
static __device__ __forceinline__ half8_t bilerp8(int4 A, int4 B, int4 C, int4 D,
                                                  float2 cc) {
    float ix = fmaf(cc.x, 8.f, 8.5f);
    float iy = fmaf(cc.y, 8.f, 8.5f);
    float xf = floorf(ix), yf = floorf(iy);
    float wx1 = ix - xf, wy1 = iy - yf;
    float wx0 = 1.f - wx1, wy0 = 1.f - wy1;
    float w00 = wy0 * wx0, w01 = wy0 * wx1, w10 = wy1 * wx0, w11 = wy1 * wx1;
    const h2_t W00 = { (_Float16)w00, (_Float16)w00 };
    const h2_t W01 = { (_Float16)w01, (_Float16)w01 };
    const h2_t W10 = { (_Float16)w10, (_Float16)w10 };
    const h2_t W11 = { (_Float16)w11, (_Float16)w11 };
    const h2_t K02 = { (_Float16)0.2f, (_Float16)0.2f };
    auto bl = [&](int a, int b, int c, int d) -> int {
        h2_t v = bc_h2(a) * W00;
        v = bc_h2(b) * W01 + v;
        v = bc_h2(c) * W10 + v;
        v = bc_h2(d) * W11 + v;
        return bc_i(pk_max(v, v * K02));   // leaky 0.2
    };
    int4 t;
    t.x = bl(A.x, B.x, C.x, D.x);
    t.y = bl(A.y, B.y, C.y, D.y);
    t.z = bl(A.z, B.z, C.z, D.z);
    t.w = bl(A.w, B.w, C.w, D.w);
    return __builtin_bit_cast(half8_t, t);
}

// G1[cell][o] = sum_c W1[o][c]*grid[c][cell] + b1[o]  (border cells = b1: bilinear
// weights sum to 1, so bilinear(G1') == bilinear(W1·g) + b1). f16, stride 24.
__global__ __launch_bounds__(64) void fuse_grid_k(const float* __restrict__ grid,
                                                  const float* __restrict__ W1,
                                                  const float* __restrict__ b1,
                                                  __half* __restrict__ G1) {
    int cell = blockIdx.x * 64 + threadIdx.x;
    if (cell >= NCELL) return;
    int yy = (cell * 3641) >> 16;          // /18
    int xx = cell - yy * 18;
    bool border = (yy == 0) | (yy == 17) | (xx == 0) | (xx == 17);
    int base = border ? 0 : ((yy - 1) * 16 + (xx - 1));
    float g[8];
    #pragma unroll
    for (int c = 0; c < 8; ++c) g[c] = grid[c * 256 + base];
    float m = border ? 0.f : 1.f;
    __align__(16) __half tmp[24];
    #pragma unroll
    for (int o = 0; o < 16; ++o) {
        float a = 0.f;
        #pragma unroll
        for (int c = 0; c < 8; ++c) a = fmaf(W1[o * 8 + c], g[c], a);
        tmp[o] = __float2half(fmaf(a, m, b1[o]));
    }
    #pragma unroll
    for (int o = 16; o < 24; ++o) tmp[o] = __float2half(0.f);
    int4* dst = reinterpret_cast<int4*>(G1 + cell * CST);
    const int4* src = reinterpret_cast<const int4*>(tmp);
    dst[0] = src[0]; dst[1] = src[1]; dst[2] = src[2];
}

// 256 threads, (256,4) regalloc regime (r10-proven). 2048 px per block (two
// 1024-px chunks) halves the per-block staging overhead. FULL=true removes all
// bounds checks (npix divisible by 2048 — true for the 8.4M-px shape).
template <bool FULL>
__global__ __launch_bounds__(256, 4) void mlp_main(
    const float* __restrict__ xin, const __half* __restrict__ G1,
    const float* __restrict__ W2, const float* __restrict__ b2,
    const float* __restrict__ W3, const float* __restrict__ b3,
    float* __restrict__ out, int npix)
{
    __shared__ __align__(16) _Float16 sG[G1H];   // 15552 B — the ONLY LDS
    const int tid = threadIdx.x;

    {   // stage fused grid once per block (972 int4 chunks)
        const int4* src = reinterpret_cast<const int4*>(G1);
        int4* dst = reinterpret_cast<int4*>(sG);
        #pragma unroll
        for (int k = 0; k < 4; ++k) {
            int i = tid + k * 256;
            if (i < G1H / 8) dst[i] = src[i];
        }
    }

    const int lane = tid & 63;
    const int hi   = lane >> 5;      // K-half selector
    const int r    = lane & 31;      // A-row / B-col
    const int wv   = tid >> 6;

    // ---- A-frag for layer 2 (32x32x16: row = lane&31, k = 8*hi + j) — r10-verified ----
    half8_t A2;
    #pragma unroll
    for (int j = 0; j < 8; ++j) A2[j] = (_Float16)0.f;
    if (r < 16) {
        const float4 u0 = *reinterpret_cast<const float4*>(W2 + r * 16 + hi * 8);
        const float4 u1 = *reinterpret_cast<const float4*>(W2 + r * 16 + hi * 8 + 4);
        A2[0] = (_Float16)u0.x; A2[1] = (_Float16)u0.y; A2[2] = (_Float16)u0.z; A2[3] = (_Float16)u0.w;
        A2[4] = (_Float16)u1.x; A2[5] = (_Float16)u1.y; A2[6] = (_Float16)u1.z; A2[7] = (_Float16)u1.w;
    }

    // ---- b2 as MFMA C-in (C/D row = (reg&3)+8*(reg>>2)+4*hi) — r10-HW-verified ----
    f32x16_t b2v;
    #pragma unroll
    for (int j = 0; j < 16; ++j) b2v[j] = 0.f;
    {
        const float4 q0 = *reinterpret_cast<const float4*>(b2 + 4 * hi);
        const float4 q1 = *reinterpret_cast<const float4*>(b2 + 8 + 4 * hi);
        b2v[0] = q0.x; b2v[1] = q0.y; b2v[2] = q0.z; b2v[3] = q0.w;
        b2v[4] = q1.x; b2v[5] = q1.y; b2v[6] = q1.z; b2v[7] = q1.w;
    }

    // ---- per-lane layer-3 W3 fragment: acc reg j holds row n(j)=(j<4?4hi+j:4+4hi+j) ----
    h2_t W3L[3][4];
    #pragma unroll
    for (int o = 0; o < 3; ++o) {
        const float4 u0 = *reinterpret_cast<const float4*>(W3 + o * 16 + 4 * hi);
        const float4 u1 = *reinterpret_cast<const float4*>(W3 + o * 16 + 8 + 4 * hi);
        W3L[o][0] = mkh2(u0.x, u0.y); W3L[o][1] = mkh2(u0.z, u0.w);
        W3L[o][2] = mkh2(u1.x, u1.y); W3L[o][3] = mkh2(u1.z, u1.w);
    }
    const float b3s0 = b3[0], b3s1 = b3[1], b3s2 = b3[2];

    __syncthreads();

    const h2_t K02 = { (_Float16)0.2f, (_Float16)0.2f };
    const float2* xp = reinterpret_cast<const float2*>(xin);   // int-indexed

    #pragma unroll
    for (int ch = 0; ch < 2; ++ch) {
        const int wbase = blockIdx.x * 2048 + ch * 1024 + wv * 256;

        // ---- hoist coord loads for the 4 sub-iters (latency overlap) ----
        float2 cc0v[4], cc1v[4];
        #pragma unroll
        for (int u = 0; u < 4; ++u) {
            int p0 = wbase + u * 64 + r;
            int p1 = p0 + 32;
            if (FULL) {
                cc0v[u] = xp[p0];
                cc1v[u] = xp[p1];
            } else {
                cc0v[u] = (p0 < npix) ? xp[p0] : make_float2(0.f, 0.f);
                cc1v[u] = (p1 < npix) ? xp[p1] : make_float2(0.f, 0.f);
            }
        }

        #pragma unroll
        for (int u = 0; u < 4; ++u) {
            const int base = wbase + u * 64;

            // ---- issue ALL 8 ds_read_b128 before either blend (latency overlap) ----
            const _Float16* gpA = sG + cell_of(cc0v[u]) * CST + 8 * hi;
            const _Float16* gpB = sG + cell_of(cc1v[u]) * CST + 8 * hi;
            int4 a0 = *reinterpret_cast<const int4*>(gpA);
            int4 a1 = *reinterpret_cast<const int4*>(gpA + CST);
            int4 a2 = *reinterpret_cast<const int4*>(gpA + 18 * CST);
            int4 a3 = *reinterpret_cast<const int4*>(gpA + 19 * CST);
            int4 bb0 = *reinterpret_cast<const int4*>(gpB);
            int4 bb1 = *reinterpret_cast<const int4*>(gpB + CST);
            int4 bb2 = *reinterpret_cast<const int4*>(gpB + 18 * CST);
            int4 bb3 = *reinterpret_cast<const int4*>(gpB + 19 * CST);

            half8_t fA = bilerp8(a0, a1, a2, a3, cc0v[u]);    // px base+r,    ch 8hi..
            half8_t fB = bilerp8(bb0, bb1, bb2, bb3, cc1v[u]); // px base+32+r, ch 8hi..

            f32x16_t acc0 = __builtin_amdgcn_mfma_f32_32x32x16_f16(A2, fA, b2v, 0, 0, 0);
            f32x16_t acc1 = __builtin_amdgcn_mfma_f32_32x32x16_f16(A2, fB, b2v, 0, 0, 0);

            // ---- h2 = leaky(acc) in packed f16 (b2 already in via C-in) ----
            h2_t hA[4], hB[4];
            #pragma unroll
            for (int p = 0; p < 4; ++p) {
                h2_t vA = mkh2(acc0[2 * p], acc0[2 * p + 1]);   // v_cvt_pkrtz
                h2_t vB = mkh2(acc1[2 * p], acc1[2 * p + 1]);
                hA[p] = pk_max(vA, vA * K02);
                hB[p] = pk_max(vB, vB * K02);
            }

            // ---- layer 3 half-partials via v_dot2_f32_f16 (8 rows per lane) ----
            float pA0 = dot2f(W3L[0][3], hA[3], dot2f(W3L[0][2], hA[2],
                        dot2f(W3L[0][1], hA[1], dot2f(W3L[0][0], hA[0], 0.f))));
            float pA1 = dot2f(W3L[1][3], hA[3], dot2f(W3L[1][2], hA[2],
                        dot2f(W3L[1][1], hA[1], dot2f(W3L[1][0], hA[0], 0.f))));
            float pA2 = dot2f(W3L[2][3], hA[3], dot2f(W3L[2][2], hA[2],
                        dot2f(W3L[2][1], hA[1], dot2f(W3L[2][0], hA[0], 0.f))));
            float pB0 = dot2f(W3L[0][3], hB[3], dot2f(W3L[0][2], hB[2],
                        dot2f(W3L[0][1], hB[1], dot2f(W3L[0][0], hB[0], 0.f))));
            float pB1 = dot2f(W3L[1][3], hB[3], dot2f(W3L[1][2], hB[2],
                        dot2f(W3L[1][1], hB[1], dot2f(W3L[1][0], hB[0], 0.f))));
            float pB2 = dot2f(W3L[2][3], hB[3], dot2f(W3L[2][2], hB[2],
                        dot2f(W3L[2][1], hB[1], dot2f(W3L[2][0], hB[0], 0.f))));

            // ---- combine half-partials across hi with 3 shfl_xor(32) (r13-verified) ----
            float sel0 = hi ? pA0 : pB0;
            float sel1 = hi ? pA1 : pB1;
            float sel2 = hi ? pA2 : pB2;
            float got0 = __shfl_xor(sel0, 32);
            float got1 = __shfl_xor(sel1, 32);
            float got2 = __shfl_xor(sel2, 32);
            float y0 = (hi ? pB0 : pA0) + got0 + b3s0;
            float y1 = (hi ? pB1 : pA1) + got1 + b3s1;
            float y2 = (hi ? pB2 : pA2) + got2 + b3s2;

            // ---- every lane stores its own pixel ----
            const int pv = base + lane;
            if (FULL || pv < npix) {
                float* po = out + pv * 3;
                po[0] = sigmoid_f(y0);
                po[1] = sigmoid_f(y1);
                po[2] = sigmoid_f(y2);
            }
        }
    }
}

extern "C" void kernel_launch(void* const* d_in, const int* in_sizes, int n_in,
                              void* d_out, int out_size, void* d_ws, size_t ws_size,
                              hipStream_t stream)
{
    const float* xin  = (const float*)d_in[0];
    const float* grid = (const float*)d_in[1];
    const float* W1   = (const float*)d_in[2];
    const float* b1   = (const float*)d_in[3];
    const float* W2   = (const float*)d_in[4];
    const float* b2   = (const float*)d_in[5];
    const float* W3   = (const float*)d_in[6];
    const float* b3   = (const float*)d_in[7];
    float* out = (float*)d_out;

    int npix = in_sizes[0] / 2;
    __half* g1 = (__half*)d_ws;   // 15552 B

    fuse_grid_k<<<(NCELL + 63) / 64, 64, 0, stream>>>(grid, W1, b1, g1);
    if (npix % 2048 == 0) {
        int nb = npix / 2048;     // exact cover, no bounds checks
        mlp_main<true><<<nb, 256, 0, stream>>>(xin, g1, W2, b2, W3, b3, out, npix);
    } else {
        int nb = (npix + 2047) / 2048;
        mlp_main<false><<<nb, 256, 0, stream>>>(xin, g1, W2, b2, W3, b3, out, npix);
    }
}